// Round 9
// baseline (125.288 us; speedup 1.0000x reference)
//
#include <hip/hip_runtime.h>
#include <hip/hip_bf16.h>
#include <math.h>

// Problem constants (fixed by reference: b=2, h=w=64, dim=256, attn_dim=128, HEAD=4)
#define N_TOK 4096
#define C_DIM 256
#define A_DIM 128
#define HEADS 4
#define HD    32
#define NBAT  2
#define BH    (NBAT * HEADS)

// (1/sqrt(32)) * log2(e) — folded into Wq at pack time
#define SCALE_LOG2E 0.25503521f

#define SPLITS 4
#define KEYS_PER_SPLIT (N_TOK / SPLITS)

// padded LDS strides (shorts): row-start bank spread -> <=2-way conflicts (free)
#define KS 40
#define VS 72

typedef __attribute__((ext_vector_type(8))) short short8;   // 8 bf16 frag
typedef __attribute__((ext_vector_type(4))) short short4_t; // 4 bf16
typedef __attribute__((ext_vector_type(4))) float floatx4;  // MFMA C/D frag

__device__ __forceinline__ unsigned short f2bf(float f) {   // RNE
    unsigned int u = __float_as_uint(f);
    u = (u + 0x7fffu + ((u >> 16) & 1u)) >> 16;
    return (unsigned short)u;
}
__device__ __forceinline__ float bf2f(unsigned short u) {
    return __uint_as_float((unsigned int)u << 16);
}
// pack two floats to bf16x2 (round-half-up/away), lo = a, hi = b.
// v_perm_b32 via __byte_perm (CUDA semantics: sel nibbles 0-3 pick x bytes,
// 4-7 pick y bytes; 0x7632 -> [x.b2,x.b3,y.b2,y.b3] = x>>16 | (y&hi16)).
// BIT-IDENTICAL to the R5/R7-verified 5-op bit pack; 3 VALU ops.
// NOTE (R4): raw v_cvt_pk_bf16_f32 inline-asm FAILED (absmax 5.7e-2); this
// perm form keeps the verified rounding exactly.
__device__ __forceinline__ unsigned int pack2(float a, float b) {
    return __byte_perm(__float_as_uint(a) + 0x8000u,
                       __float_as_uint(b) + 0x8000u, 0x7632);
}

// ---------------------------------------------------------------------------
// In-register quad transpose of packed bf16 key-pairs (verified R3/R5/R7).
// Input per lane (quad q):
//   a0 = keys(4q,4q+1), a1 = keys(4q+2,4q+3)          [key-frag 0..15]
//   a2 = keys(16+4q,..), a3 = keys(16+4q+2,..)        [key-frag 16..31]
// Output: PV A-frag — lane holds keys 8q..8q+7 as 4 packed words.
// ---------------------------------------------------------------------------
__device__ __forceinline__ short8 quad_xpose(unsigned int a0, unsigned int a1,
                                             unsigned int a2, unsigned int a3,
                                             int lane)
{
    union { unsigned int u[4]; short8 s; } cv;
#if __has_builtin(__builtin_amdgcn_permlane32_swap) && __has_builtin(__builtin_amdgcn_permlane16_swap)
    (void)lane;
    auto s0 = __builtin_amdgcn_permlane32_swap(a0, a2, false, false);
    auto s1 = __builtin_amdgcn_permlane32_swap(a1, a3, false, false);
    auto t0 = __builtin_amdgcn_permlane16_swap(s0[0], s0[1], false, false);
    auto t1 = __builtin_amdgcn_permlane16_swap(s1[0], s1[1], false, false);
    cv.u[0] = t0[0]; cv.u[1] = t1[0]; cv.u[2] = t0[1]; cv.u[3] = t1[1];
#else
    // Fallback: shfl_xor(32) for the half swap, ds_swizzle xor-16 for quads.
    const int hi32 = (lane >> 5) & 1;
    const int u16  = (lane >> 4) & 1;
    unsigned int x0 = __shfl_xor(a2, 32), x2 = __shfl_xor(a0, 32);
    unsigned int r0 = hi32 ? x0 : a0;
    unsigned int r1 = hi32 ? a2 : x2;
    unsigned int y0 = __shfl_xor(a3, 32), y2 = __shfl_xor(a1, 32);
    unsigned int r0b = hi32 ? y0 : a1;
    unsigned int r1b = hi32 ? a3 : y2;
    unsigned int w0 = (unsigned int)__builtin_amdgcn_ds_swizzle((int)r1, 0x401F);
    unsigned int w1 = (unsigned int)__builtin_amdgcn_ds_swizzle((int)r0, 0x401F);
    unsigned int w2 = (unsigned int)__builtin_amdgcn_ds_swizzle((int)r1b, 0x401F);
    unsigned int w3 = (unsigned int)__builtin_amdgcn_ds_swizzle((int)r0b, 0x401F);
    cv.u[0] = u16 ? w0 : r0;
    cv.u[1] = u16 ? w2 : r0b;
    cv.u[2] = u16 ? r1 : w1;
    cv.u[3] = u16 ? r1b : w3;
#endif
    return cv.s;
}

// ---------------------------------------------------------------------------
// K0: pack weights fp32 -> bf16 in B-fragment order.
// Layout: Wp[wid][step s][tile t][lane][j]  (wid: 0=Wq(scaled) 1=Wk 2=Wv 3=Wo)
// ---------------------------------------------------------------------------
__global__ __launch_bounds__(256) void wpack_kernel(
    const float* __restrict__ Wq, const float* __restrict__ Wk,
    const float* __restrict__ Wv, const float* __restrict__ Wo,
    unsigned short* __restrict__ Wp)
{
    const int chunk = blockIdx.x * 256 + threadIdx.x;  // [0, 16384): 8 shorts each
    const int wid = chunk >> 12;
    const int c = chunk & 4095;
    const int lane = c & 63, quad = lane >> 4, l15 = lane & 15;
    short8 v;
    if (wid < 3) {
        const int s = c >> 9, t = (c >> 6) & 7;
        const float* W = (wid == 0) ? Wq : ((wid == 1) ? Wk : Wv);
        const float scale = (wid == 0) ? SCALE_LOG2E : 1.0f;
        const int src = (s * 32 + quad * 8) * A_DIM + t * 16 + l15;
        #pragma unroll
        for (int j = 0; j < 8; j++) v[j] = (short)f2bf(W[src + j * A_DIM] * scale);
    } else {
        const int s = c >> 10, t = (c >> 6) & 15;
        const int src = (s * 32 + quad * 8) * C_DIM + t * 16 + l15;
        #pragma unroll
        for (int j = 0; j < 8; j++) v[j] = (short)f2bf(Wo[src + j * C_DIM]);
    }
    *(short8*)(Wp + (long)chunk * 8) = v;
}

// ---------------------------------------------------------------------------
// K1: QKV projection via MFMA. 512 blocks x 4 waves.
// A-frag f32->bf16 conversion via perm-pack pairs (3 ops / 2 elements,
// round-half-up; differs from prior RNE only on exact-tie mantissas).
// ---------------------------------------------------------------------------
__global__ __launch_bounds__(256) void qkv_kernel(
    const float* __restrict__ query, const float* __restrict__ context,
    const unsigned short* __restrict__ Wp,
    unsigned short* __restrict__ Qb, unsigned short* __restrict__ Kb,
    unsigned short* __restrict__ Vb)
{
    __shared__ __align__(16) unsigned short V_lds[128 * 18];  // [col][tok16+pad] 4.5KB

    const int tid = threadIdx.x;
    const int w = tid >> 6, lane = tid & 63;
    const int quad = lane >> 4, l15 = lane & 15;
    const int ch = w;                      // col quarter (32 cols)
    const long i0 = (long)blockIdx.x * 16;
    const long row = i0 + l15;

    const unsigned short* Wqp = Wp;
    const unsigned short* Wkp = Wp + 32768;
    const unsigned short* Wvp = Wp + 65536;

    floatx4 aQ[2] = {}, aK[2] = {}, aV[2] = {};

    for (int s = 0; s < 8; s++) {
        const float* qp = query + row * C_DIM + s * 32 + quad * 8;
        const float* cp = context + row * C_DIM + s * 32 + quad * 8;
        floatx4 q0 = *(const floatx4*)qp, q1 = *(const floatx4*)(qp + 4);
        floatx4 c0 = *(const floatx4*)cp, c1 = *(const floatx4*)(cp + 4);
        union { unsigned int u[4]; short8 s8; } aq, ac;
        aq.u[0] = pack2(q0[0], q0[1]); aq.u[1] = pack2(q0[2], q0[3]);
        aq.u[2] = pack2(q1[0], q1[1]); aq.u[3] = pack2(q1[2], q1[3]);
        ac.u[0] = pack2(c0[0], c0[1]); ac.u[1] = pack2(c0[2], c0[3]);
        ac.u[2] = pack2(c1[0], c1[1]); ac.u[3] = pack2(c1[2], c1[3]);
        #pragma unroll
        for (int tp = 0; tp < 2; tp++) {
            const long fo = ((long)(s * 8 + ch * 2 + tp) * 64 + lane) * 8;
            short8 bq = *(const short8*)(Wqp + fo);
            short8 bk = *(const short8*)(Wkp + fo);
            short8 bv = *(const short8*)(Wvp + fo);
            aQ[tp] = __builtin_amdgcn_mfma_f32_16x16x32_bf16(aq.s8, bq, aQ[tp], 0, 0, 0);
            aK[tp] = __builtin_amdgcn_mfma_f32_16x16x32_bf16(ac.s8, bk, aK[tp], 0, 0, 0);
            aV[tp] = __builtin_amdgcn_mfma_f32_16x16x32_bf16(ac.s8, bv, aV[tp], 0, 0, 0);
        }
    }

    const long b = i0 >> 12;
    const long n0 = i0 & (N_TOK - 1);
    const long nbase = n0 + quad * 4;
    #pragma unroll
    for (int tp = 0; tp < 2; tp++) {
        const int col = ch * 32 + tp * 16 + l15;
        const int h = col >> 5, d = col & 31;
        unsigned short* qdst = Qb + ((b * HEADS + h) * N_TOK + nbase) * HD + d;
        unsigned short* kdst = Kb + ((b * HEADS + h) * N_TOK + nbase) * HD + d;
        #pragma unroll
        for (int r = 0; r < 4; r++) {
            qdst[r * HD] = f2bf(aQ[tp][r]);
            kdst[r * HD] = f2bf(aK[tp][r]);
        }
        short4_t pv;
        #pragma unroll
        for (int r = 0; r < 4; r++) pv[r] = (short)f2bf(aV[tp][r]);
        *(short4_t*)&V_lds[col * 18 + quad * 4] = pv;
    }
    __syncthreads();

    {   // cooperative V^T write-out: 128 cols x 16 tokens; 16B chunks
        const int col = tid >> 1, seg = tid & 1;
        const int h = col >> 5, d = col & 31;
        unsigned short* dst = Vb + ((b * HEADS + h) * HD + d) * N_TOK + n0 + seg * 8;
        *(short8*)dst = *(const short8*)&V_lds[col * 18 + seg * 8];
    }
}

// ---------------------------------------------------------------------------
// K2: flash attention, no-max softmax, split-K=4, S^T formulation.
//  - Cooperative K/V LDS staging, double-buffered, 1 barrier/tile, depth-2
//    global prefetch (verified R5/R7).
//  - P^T -> P transpose fully in-register (quad_xpose, verified R3/R5/R7).
//  - Denominator on the MFMA pipe via ones-column (verified R7).
//  - pack2 now 3-op v_perm form (bit-identical rounding).
// ---------------------------------------------------------------------------
__global__ __launch_bounds__(256, 4) void attn_kernel(
    const unsigned short* __restrict__ Qb, const unsigned short* __restrict__ Kb,
    const unsigned short* __restrict__ Vb,
    unsigned short* __restrict__ AO, float* __restrict__ Lbuf)
{
    __shared__ __align__(16) unsigned short K_lds[2][64 * KS];   // 2 x 5 KB
    __shared__ __align__(16) unsigned short V_lds[2][HD * VS];   // 2 x 4.5 KB

    const int tid  = threadIdx.x;
    const int w    = tid >> 6;
    const int lane = tid & 63;
    const int quad = lane >> 4;
    const int l15  = lane & 15;

    // XCD swizzle: blocks with equal (bh,z) share L%8 -> same XCD L2.
    const int L  = blockIdx.x;
    const int g  = (L & 7) + 8 * ((L >> 3) >> 5);  // group 0..31
    const int qb = (L >> 3) & 31;                  // q-block 0..31
    const int bh = g & 7;
    const int z  = g >> 3;                         // 0..SPLITS-1
    const int i0 = qb * 128 + w * 32;

    const unsigned short* Qh = Qb + (long)bh * N_TOK * HD;
    const unsigned short* Kh = Kb + (long)bh * N_TOK * HD;
    const unsigned short* Vh = Vb + (long)bh * HD * N_TOK;

    const short8 qfA = *(const short8*)(Qh + (long)(i0 + l15) * HD + quad * 8);
    const short8 qfB = *(const short8*)(Qh + (long)(i0 + 16 + l15) * HD + quad * 8);

    // all-ones bf16 B-fragment for the denominator MFMA
    const short8 onesf = {(short)0x3F80, (short)0x3F80, (short)0x3F80, (short)0x3F80,
                          (short)0x3F80, (short)0x3F80, (short)0x3F80, (short)0x3F80};

    floatx4 accA0 = {0.f,0.f,0.f,0.f}, accA1 = {0.f,0.f,0.f,0.f};
    floatx4 accB0 = {0.f,0.f,0.f,0.f}, accB1 = {0.f,0.f,0.f,0.f};
    floatx4 denA  = {0.f,0.f,0.f,0.f}, denB  = {0.f,0.f,0.f,0.f};

    const int  kst = (tid >> 2) * KS + (tid & 3) * 8;   // K stage: row tid>>2
    const int  vst = (tid >> 3) * VS + (tid & 7) * 8;   // V stage: dim tid>>3
    const long vgl = (long)(tid >> 3) * N_TOK + (tid & 7) * 8;

    const int j_lo = z * KEYS_PER_SPLIT;
    const int nt   = KEYS_PER_SPLIT / 64;               // 16 tiles

    // prologue: stage tile 0, prefetch tile 1 into registers
    short8 kreg = *(const short8*)(Kh + (long)j_lo * HD + tid * 8);
    short8 vreg = *(const short8*)(Vh + vgl + j_lo);
    *(short8*)&K_lds[0][kst] = kreg;
    *(short8*)&V_lds[0][vst] = vreg;
    kreg = *(const short8*)(Kh + (long)(j_lo + 64) * HD + tid * 8);
    vreg = *(const short8*)(Vh + vgl + j_lo + 64);
    __syncthreads();

    #pragma unroll 1
    for (int t = 0; t < nt; ++t) {
        const int cur = t & 1;

        #pragma unroll
        for (int sub = 0; sub < 2; sub++) {
            const int jb = sub * 32;
            short8 kf0 = *(short8*)&K_lds[cur][(jb + l15) * KS + quad * 8];
            short8 kf1 = *(short8*)&K_lds[cur][(jb + 16 + l15) * KS + quad * 8];
            const floatx4 zf = {0.f,0.f,0.f,0.f};
            // S^T = K · Q^T : C rows = keys, cols = queries
            floatx4 sA0 = __builtin_amdgcn_mfma_f32_16x16x32_bf16(kf0, qfA, zf, 0, 0, 0);
            floatx4 sA1 = __builtin_amdgcn_mfma_f32_16x16x32_bf16(kf1, qfA, zf, 0, 0, 0);
            floatx4 sB0 = __builtin_amdgcn_mfma_f32_16x16x32_bf16(kf0, qfB, zf, 0, 0, 0);
            floatx4 sB1 = __builtin_amdgcn_mfma_f32_16x16x32_bf16(kf1, qfB, zf, 0, 0, 0);

            floatx4 pA0, pA1, pB0, pB1;
            #pragma unroll
            for (int r = 0; r < 4; r++) {
                pA0[r] = __builtin_amdgcn_exp2f(sA0[r]);
                pA1[r] = __builtin_amdgcn_exp2f(sA1[r]);
                pB0[r] = __builtin_amdgcn_exp2f(sB0[r]);
                pB1[r] = __builtin_amdgcn_exp2f(sB1[r]);
            }

            // pack key pairs (3-op perm) and transpose quads in-register
            short8 pfA = quad_xpose(pack2(pA0[0], pA0[1]), pack2(pA0[2], pA0[3]),
                                    pack2(pA1[0], pA1[1]), pack2(pA1[2], pA1[3]), lane);
            short8 pfB = quad_xpose(pack2(pB0[0], pB0[1]), pack2(pB0[2], pB0[3]),
                                    pack2(pB1[0], pB1[1]), pack2(pB1[2], pB1[3]), lane);

            short8 vf0 = *(short8*)&V_lds[cur][l15 * VS + jb + quad * 8];
            short8 vf1 = *(short8*)&V_lds[cur][(16 + l15) * VS + jb + quad * 8];
            accA0 = __builtin_amdgcn_mfma_f32_16x16x32_bf16(pfA, vf0, accA0, 0, 0, 0);
            accA1 = __builtin_amdgcn_mfma_f32_16x16x32_bf16(pfA, vf1, accA1, 0, 0, 0);
            accB0 = __builtin_amdgcn_mfma_f32_16x16x32_bf16(pfB, vf0, accB0, 0, 0, 0);
            accB1 = __builtin_amdgcn_mfma_f32_16x16x32_bf16(pfB, vf1, accB1, 0, 0, 0);
            // denominator on the MFMA pipe: every output col = row-sum of P
            denA  = __builtin_amdgcn_mfma_f32_16x16x32_bf16(pfA, onesf, denA, 0, 0, 0);
            denB  = __builtin_amdgcn_mfma_f32_16x16x32_bf16(pfB, onesf, denB, 0, 0, 0);
        }

        if (t + 1 < nt) {
            // stage tile t+1 (regs loaded 1 tile ago -> vmcnt long satisfied)
            *(short8*)&K_lds[cur ^ 1][kst] = kreg;
            *(short8*)&V_lds[cur ^ 1][vst] = vreg;
            if (t + 2 < nt) {   // depth-2 prefetch
                kreg = *(const short8*)(Kh + (long)(j_lo + (t + 2) * 64) * HD + tid * 8);
                vreg = *(const short8*)(Vh + vgl + j_lo + (t + 2) * 64);
            }
            __syncthreads();   // one barrier per tile: orders write(buf^1) vs read
        }
    }

    // denA[r] holds denom(query i0+quad*4+r), replicated across the 16 l15
    // lanes of the quad — exactly the C-frag row layout the epilogue needs.
    const int b = bh >> 2, h = bh & 3;
    unsigned short* AOz = AO + (long)z * (NBAT * N_TOK * A_DIM);
    float* Lz = Lbuf + (long)z * (BH * N_TOK);
    if (l15 == 0) {   // one lane per quad writes 4+4 denominators
        #pragma unroll
        for (int r = 0; r < 4; r++) {
            Lz[(long)bh * N_TOK + i0 + quad * 4 + r]      = denA[r];
            Lz[(long)bh * N_TOK + i0 + 16 + quad * 4 + r] = denB[r];
        }
    }
    #pragma unroll
    for (int r = 0; r < 4; r++) {
        const float invA = 1.0f / denA[r];
        const float invB = 1.0f / denB[r];
        const long rowA = (long)b * N_TOK + i0 + quad * 4 + r;
        const long rowB = rowA + 16;
        AOz[rowA * A_DIM + h * HD + l15]      = f2bf(accA0[r] * invA);
        AOz[rowA * A_DIM + h * HD + 16 + l15] = f2bf(accA1[r] * invA);
        AOz[rowB * A_DIM + h * HD + l15]      = f2bf(accB0[r] * invB);
        AOz[rowB * A_DIM + h * HD + 16 + l15] = f2bf(accB1[r] * invB);
    }
}

// ---------------------------------------------------------------------------
// K3: split-K combine + out-projection via MFMA. 512 blocks x 4 waves.
// ---------------------------------------------------------------------------
__global__ __launch_bounds__(256) void outproj_kernel(
    const unsigned short* __restrict__ AO, const float* __restrict__ Lbuf,
    const unsigned short* __restrict__ Wp, float* __restrict__ out)
{
    const int tid = threadIdx.x;
    const int w = tid >> 6, lane = tid & 63;
    const int quad = lane >> 4, l15 = lane & 15;
    const int ch = w;                       // col quarter (64 cols)
    const long i0 = (long)blockIdx.x * 16;
    const long row = i0 + l15;
    const int b = (int)(row >> 12);
    const int n = (int)(row & (N_TOK - 1));
    const unsigned short* Wop = Wp + 98304;

    floatx4 acc[4] = {};

    #pragma unroll
    for (int s = 0; s < 4; s++) {   // k-step == head s (32-aligned)
        float lz[SPLITS], lsum = 0.f;
        #pragma unroll
        for (int z = 0; z < SPLITS; z++) {
            lz[z] = Lbuf[(long)z * (BH * N_TOK) + (long)(b * HEADS + s) * N_TOK + n];
            lsum += lz[z];
        }
        const float inv = 1.0f / lsum;
        float vals[8] = {};
        #pragma unroll
        for (int z = 0; z < SPLITS; z++) {
            short8 az = *(const short8*)(AO + (long)z * (NBAT * N_TOK * A_DIM) +
                                         row * A_DIM + s * 32 + quad * 8);
            const float wz = lz[z] * inv;
            #pragma unroll
            for (int j = 0; j < 8; j++) vals[j] += wz * bf2f((unsigned short)az[j]);
        }
        union { unsigned int u[4]; short8 s8; } af;
        af.u[0] = pack2(vals[0], vals[1]); af.u[1] = pack2(vals[2], vals[3]);
        af.u[2] = pack2(vals[4], vals[5]); af.u[3] = pack2(vals[6], vals[7]);
        #pragma unroll
        for (int tp = 0; tp < 4; tp++) {
            const int t = ch * 4 + tp;
            short8 bo = *(const short8*)(Wop + ((long)(s * 16 + t) * 64 + lane) * 8);
            acc[tp] = __builtin_amdgcn_mfma_f32_16x16x32_bf16(af.s8, bo, acc[tp], 0, 0, 0);
        }
    }

    #pragma unroll
    for (int tp = 0; tp < 4; tp++) {
        #pragma unroll
        for (int r = 0; r < 4; r++)
            out[(i0 + quad * 4 + r) * C_DIM + (ch * 4 + tp) * 16 + l15] = acc[tp][r];
    }
}

// ---------------------------------------------------------------------------
extern "C" void kernel_launch(void* const* d_in, const int* in_sizes, int n_in,
                              void* d_out, int out_size, void* d_ws, size_t ws_size,
                              hipStream_t stream)
{
    const float* query   = (const float*)d_in[0];
    const float* context = (const float*)d_in[1];
    const float* Wq      = (const float*)d_in[2];
    const float* Wk      = (const float*)d_in[3];
    const float* Wv      = (const float*)d_in[4];
    const float* Wo      = (const float*)d_in[5];
    float* out = (float*)d_out;

    char* ws = (char*)d_ws;
    unsigned short* Qb = (unsigned short*)(ws);                    // 2 MB [bh][n][32]
    unsigned short* Kb = (unsigned short*)(ws + (2 << 20));        // 2 MB [bh][n][32]
    unsigned short* Vb = (unsigned short*)(ws + (4 << 20));        // 2 MB [bh][32][n]
    unsigned short* AO = (unsigned short*)(ws + (6 << 20));        // 8 MB [4][b*n][128] bf16
    float*          Lb = (float*)(ws + (22 << 20));                // 512 KB [4][bh][n]
    unsigned short* Wp = (unsigned short*)(ws + (23 << 20));       // 256 KB packed

    wpack_kernel<<<dim3(64), dim3(256), 0, stream>>>(Wq, Wk, Wv, Wo, Wp);
    qkv_kernel<<<dim3(512), dim3(256), 0, stream>>>(query, context, Wp, Qb, Kb, Vb);
    attn_kernel<<<dim3(32 * BH * SPLITS), dim3(256), 0, stream>>>(
        Qb, Kb, Vb, AO, Lb);
    outproj_kernel<<<dim3(512), dim3(256), 0, stream>>>(AO, Lb, Wp, out);
}

// Round 10
// 123.834 us; speedup vs baseline: 1.0117x; 1.0117x over previous
//
#include <hip/hip_runtime.h>
#include <hip/hip_bf16.h>
#include <math.h>

// Problem constants (fixed by reference: b=2, h=w=64, dim=256, attn_dim=128, HEAD=4)
#define N_TOK 4096
#define C_DIM 256
#define A_DIM 128
#define HEADS 4
#define HD    32
#define NBAT  2
#define BH    (NBAT * HEADS)

// (1/sqrt(32)) * log2(e) — folded into Wq at pack time
#define SCALE_LOG2E 0.25503521f

#define SPLITS 4
#define KEYS_PER_SPLIT (N_TOK / SPLITS)

// padded LDS strides (shorts): row-start bank spread -> <=2-way conflicts (free)
#define KS 40
#define VS 136   // attn V stride: 128 tokens + 8 pad (same mod-32-bank pattern as 72)

typedef __attribute__((ext_vector_type(8))) short short8;   // 8 bf16 frag
typedef __attribute__((ext_vector_type(4))) short short4_t; // 4 bf16
typedef __attribute__((ext_vector_type(4))) float floatx4;  // MFMA C/D frag

__device__ __forceinline__ unsigned short f2bf(float f) {   // RNE
    unsigned int u = __float_as_uint(f);
    u = (u + 0x7fffu + ((u >> 16) & 1u)) >> 16;
    return (unsigned short)u;
}
__device__ __forceinline__ float bf2f(unsigned short u) {
    return __uint_as_float((unsigned int)u << 16);
}
// pack two floats to bf16x2 (round-half-up/away), lo = a, hi = b.
// 3-op v_perm form, bit-identical to the verified 5-op bit pack (R9: passed,
// absmax 1.95e-3; perf-neutral — kept for code size).
// NOTE (R4): raw v_cvt_pk_bf16_f32 inline-asm FAILED — never reuse unprobed.
__device__ __forceinline__ unsigned int pack2(float a, float b) {
    return __byte_perm(__float_as_uint(a) + 0x8000u,
                       __float_as_uint(b) + 0x8000u, 0x7632);
}

// ---------------------------------------------------------------------------
// In-register quad transpose of packed bf16 key-pairs (verified R3/R5/R7/R9).
// Input per lane (quad q):
//   a0 = keys(4q,4q+1), a1 = keys(4q+2,4q+3)          [key-frag 0..15]
//   a2 = keys(16+4q,..), a3 = keys(16+4q+2,..)        [key-frag 16..31]
// Output: PV A-frag — lane holds keys 8q..8q+7 as 4 packed words.
// ---------------------------------------------------------------------------
__device__ __forceinline__ short8 quad_xpose(unsigned int a0, unsigned int a1,
                                             unsigned int a2, unsigned int a3,
                                             int lane)
{
    union { unsigned int u[4]; short8 s; } cv;
#if __has_builtin(__builtin_amdgcn_permlane32_swap) && __has_builtin(__builtin_amdgcn_permlane16_swap)
    (void)lane;
    auto s0 = __builtin_amdgcn_permlane32_swap(a0, a2, false, false);
    auto s1 = __builtin_amdgcn_permlane32_swap(a1, a3, false, false);
    auto t0 = __builtin_amdgcn_permlane16_swap(s0[0], s0[1], false, false);
    auto t1 = __builtin_amdgcn_permlane16_swap(s1[0], s1[1], false, false);
    cv.u[0] = t0[0]; cv.u[1] = t1[0]; cv.u[2] = t0[1]; cv.u[3] = t1[1];
#else
    // Fallback: shfl_xor(32) for the half swap, ds_swizzle xor-16 for quads.
    const int hi32 = (lane >> 5) & 1;
    const int u16  = (lane >> 4) & 1;
    unsigned int x0 = __shfl_xor(a2, 32), x2 = __shfl_xor(a0, 32);
    unsigned int r0 = hi32 ? x0 : a0;
    unsigned int r1 = hi32 ? a2 : x2;
    unsigned int y0 = __shfl_xor(a3, 32), y2 = __shfl_xor(a1, 32);
    unsigned int r0b = hi32 ? y0 : a1;
    unsigned int r1b = hi32 ? a3 : y2;
    unsigned int w0 = (unsigned int)__builtin_amdgcn_ds_swizzle((int)r1, 0x401F);
    unsigned int w1 = (unsigned int)__builtin_amdgcn_ds_swizzle((int)r0, 0x401F);
    unsigned int w2 = (unsigned int)__builtin_amdgcn_ds_swizzle((int)r1b, 0x401F);
    unsigned int w3 = (unsigned int)__builtin_amdgcn_ds_swizzle((int)r0b, 0x401F);
    cv.u[0] = u16 ? w0 : r0;
    cv.u[1] = u16 ? w2 : r0b;
    cv.u[2] = u16 ? r1 : w1;
    cv.u[3] = u16 ? r1b : w3;
#endif
    return cv.s;
}

// ---------------------------------------------------------------------------
// K0: pack weights fp32 -> bf16 in B-fragment order.
// Layout: Wp[wid][step s][tile t][lane][j]  (wid: 0=Wq(scaled) 1=Wk 2=Wv 3=Wo)
// ---------------------------------------------------------------------------
__global__ __launch_bounds__(256) void wpack_kernel(
    const float* __restrict__ Wq, const float* __restrict__ Wk,
    const float* __restrict__ Wv, const float* __restrict__ Wo,
    unsigned short* __restrict__ Wp)
{
    const int chunk = blockIdx.x * 256 + threadIdx.x;  // [0, 16384): 8 shorts each
    const int wid = chunk >> 12;
    const int c = chunk & 4095;
    const int lane = c & 63, quad = lane >> 4, l15 = lane & 15;
    short8 v;
    if (wid < 3) {
        const int s = c >> 9, t = (c >> 6) & 7;
        const float* W = (wid == 0) ? Wq : ((wid == 1) ? Wk : Wv);
        const float scale = (wid == 0) ? SCALE_LOG2E : 1.0f;
        const int src = (s * 32 + quad * 8) * A_DIM + t * 16 + l15;
        #pragma unroll
        for (int j = 0; j < 8; j++) v[j] = (short)f2bf(W[src + j * A_DIM] * scale);
    } else {
        const int s = c >> 10, t = (c >> 6) & 15;
        const int src = (s * 32 + quad * 8) * C_DIM + t * 16 + l15;
        #pragma unroll
        for (int j = 0; j < 8; j++) v[j] = (short)f2bf(Wo[src + j * C_DIM]);
    }
    *(short8*)(Wp + (long)chunk * 8) = v;
}

// ---------------------------------------------------------------------------
// K1: QKV projection via MFMA. 512 blocks x 4 waves (unchanged from R9).
// ---------------------------------------------------------------------------
__global__ __launch_bounds__(256) void qkv_kernel(
    const float* __restrict__ query, const float* __restrict__ context,
    const unsigned short* __restrict__ Wp,
    unsigned short* __restrict__ Qb, unsigned short* __restrict__ Kb,
    unsigned short* __restrict__ Vb)
{
    __shared__ __align__(16) unsigned short V_lds[128 * 18];  // [col][tok16+pad] 4.5KB

    const int tid = threadIdx.x;
    const int w = tid >> 6, lane = tid & 63;
    const int quad = lane >> 4, l15 = lane & 15;
    const int ch = w;                      // col quarter (32 cols)
    const long i0 = (long)blockIdx.x * 16;
    const long row = i0 + l15;

    const unsigned short* Wqp = Wp;
    const unsigned short* Wkp = Wp + 32768;
    const unsigned short* Wvp = Wp + 65536;

    floatx4 aQ[2] = {}, aK[2] = {}, aV[2] = {};

    for (int s = 0; s < 8; s++) {
        const float* qp = query + row * C_DIM + s * 32 + quad * 8;
        const float* cp = context + row * C_DIM + s * 32 + quad * 8;
        floatx4 q0 = *(const floatx4*)qp, q1 = *(const floatx4*)(qp + 4);
        floatx4 c0 = *(const floatx4*)cp, c1 = *(const floatx4*)(cp + 4);
        union { unsigned int u[4]; short8 s8; } aq, ac;
        aq.u[0] = pack2(q0[0], q0[1]); aq.u[1] = pack2(q0[2], q0[3]);
        aq.u[2] = pack2(q1[0], q1[1]); aq.u[3] = pack2(q1[2], q1[3]);
        ac.u[0] = pack2(c0[0], c0[1]); ac.u[1] = pack2(c0[2], c0[3]);
        ac.u[2] = pack2(c1[0], c1[1]); ac.u[3] = pack2(c1[2], c1[3]);
        #pragma unroll
        for (int tp = 0; tp < 2; tp++) {
            const long fo = ((long)(s * 8 + ch * 2 + tp) * 64 + lane) * 8;
            short8 bq = *(const short8*)(Wqp + fo);
            short8 bk = *(const short8*)(Wkp + fo);
            short8 bv = *(const short8*)(Wvp + fo);
            aQ[tp] = __builtin_amdgcn_mfma_f32_16x16x32_bf16(aq.s8, bq, aQ[tp], 0, 0, 0);
            aK[tp] = __builtin_amdgcn_mfma_f32_16x16x32_bf16(ac.s8, bk, aK[tp], 0, 0, 0);
            aV[tp] = __builtin_amdgcn_mfma_f32_16x16x32_bf16(ac.s8, bv, aV[tp], 0, 0, 0);
        }
    }

    const long b = i0 >> 12;
    const long n0 = i0 & (N_TOK - 1);
    const long nbase = n0 + quad * 4;
    #pragma unroll
    for (int tp = 0; tp < 2; tp++) {
        const int col = ch * 32 + tp * 16 + l15;
        const int h = col >> 5, d = col & 31;
        unsigned short* qdst = Qb + ((b * HEADS + h) * N_TOK + nbase) * HD + d;
        unsigned short* kdst = Kb + ((b * HEADS + h) * N_TOK + nbase) * HD + d;
        #pragma unroll
        for (int r = 0; r < 4; r++) {
            qdst[r * HD] = f2bf(aQ[tp][r]);
            kdst[r * HD] = f2bf(aK[tp][r]);
        }
        short4_t pv;
        #pragma unroll
        for (int r = 0; r < 4; r++) pv[r] = (short)f2bf(aV[tp][r]);
        *(short4_t*)&V_lds[col * 18 + quad * 4] = pv;
    }
    __syncthreads();

    {   // cooperative V^T write-out: 128 cols x 16 tokens; 16B chunks
        const int col = tid >> 1, seg = tid & 1;
        const int h = col >> 5, d = col & 31;
        unsigned short* dst = Vb + ((b * HEADS + h) * HD + d) * N_TOK + n0 + seg * 8;
        *(short8*)dst = *(const short8*)&V_lds[col * 18 + seg * 8];
    }
}

// ---------------------------------------------------------------------------
// K2: flash attention, no-max softmax, split-K=4, S^T formulation.
// R10 change: 128-KEY TILES (was 64) -> barriers per block 16 -> 8, stage/
// barrier overhead amortized over 2x compute, 4 independent sub-chains per
// barrier window. LDS 19.5 -> 37.9 KB (still 4 blocks/CU).
//  - Cooperative K/V LDS staging, double-buffered, 1 barrier/tile, depth-2
//    global prefetch (structure verified R5/R7/R9).
//  - P^T -> P transpose fully in-register (quad_xpose).
//  - Denominator on the MFMA pipe via ones-column (verified R7/R9).
// ---------------------------------------------------------------------------
__global__ __launch_bounds__(256, 4) void attn_kernel(
    const unsigned short* __restrict__ Qb, const unsigned short* __restrict__ Kb,
    const unsigned short* __restrict__ Vb,
    unsigned short* __restrict__ AO, float* __restrict__ Lbuf)
{
    __shared__ __align__(16) unsigned short K_lds[2][128 * KS];  // 2 x 10 KB
    __shared__ __align__(16) unsigned short V_lds[2][HD * VS];   // 2 x 8.5 KB

    const int tid  = threadIdx.x;
    const int w    = tid >> 6;
    const int lane = tid & 63;
    const int quad = lane >> 4;
    const int l15  = lane & 15;

    // XCD swizzle: blocks with equal (bh,z) share L%8 -> same XCD L2.
    const int L  = blockIdx.x;
    const int g  = (L & 7) + 8 * ((L >> 3) >> 5);  // group 0..31
    const int qb = (L >> 3) & 31;                  // q-block 0..31
    const int bh = g & 7;
    const int z  = g >> 3;                         // 0..SPLITS-1
    const int i0 = qb * 128 + w * 32;

    const unsigned short* Qh = Qb + (long)bh * N_TOK * HD;
    const unsigned short* Kh = Kb + (long)bh * N_TOK * HD;
    const unsigned short* Vh = Vb + (long)bh * HD * N_TOK;

    const short8 qfA = *(const short8*)(Qh + (long)(i0 + l15) * HD + quad * 8);
    const short8 qfB = *(const short8*)(Qh + (long)(i0 + 16 + l15) * HD + quad * 8);

    // all-ones bf16 B-fragment for the denominator MFMA
    const short8 onesf = {(short)0x3F80, (short)0x3F80, (short)0x3F80, (short)0x3F80,
                          (short)0x3F80, (short)0x3F80, (short)0x3F80, (short)0x3F80};

    floatx4 accA0 = {0.f,0.f,0.f,0.f}, accA1 = {0.f,0.f,0.f,0.f};
    floatx4 accB0 = {0.f,0.f,0.f,0.f}, accB1 = {0.f,0.f,0.f,0.f};
    floatx4 denA  = {0.f,0.f,0.f,0.f}, denB  = {0.f,0.f,0.f,0.f};

    const int  kst = (tid >> 2) * KS + (tid & 3) * 8;   // K stage: rows 0..63 (+64*KS pass B)
    const int  vst = (tid >> 3) * VS + (tid & 7) * 8;   // V stage: toks 0..63 (+64 pass B)
    const long vgl = (long)(tid >> 3) * N_TOK + (tid & 7) * 8;

    const int j_lo = z * KEYS_PER_SPLIT;
    const int nt   = KEYS_PER_SPLIT / 128;              // 8 tiles of 128 keys

    // prologue: stage tile 0 (two 64-row passes), prefetch tile 1 into regs
    short8 kregA = *(const short8*)(Kh + (long)j_lo * HD + tid * 8);
    short8 kregB = *(const short8*)(Kh + (long)(j_lo + 64) * HD + tid * 8);
    short8 vregA = *(const short8*)(Vh + vgl + j_lo);
    short8 vregB = *(const short8*)(Vh + vgl + j_lo + 64);
    *(short8*)&K_lds[0][kst]           = kregA;
    *(short8*)&K_lds[0][kst + 64 * KS] = kregB;
    *(short8*)&V_lds[0][vst]           = vregA;
    *(short8*)&V_lds[0][vst + 64]      = vregB;
    kregA = *(const short8*)(Kh + (long)(j_lo + 128) * HD + tid * 8);
    kregB = *(const short8*)(Kh + (long)(j_lo + 192) * HD + tid * 8);
    vregA = *(const short8*)(Vh + vgl + j_lo + 128);
    vregB = *(const short8*)(Vh + vgl + j_lo + 192);
    __syncthreads();

    #pragma unroll 1
    for (int t = 0; t < nt; ++t) {
        const int cur = t & 1;

        #pragma unroll
        for (int sub = 0; sub < 4; sub++) {
            const int jb = sub * 32;
            short8 kf0 = *(short8*)&K_lds[cur][(jb + l15) * KS + quad * 8];
            short8 kf1 = *(short8*)&K_lds[cur][(jb + 16 + l15) * KS + quad * 8];
            const floatx4 zf = {0.f,0.f,0.f,0.f};
            // S^T = K · Q^T : C rows = keys, cols = queries
            floatx4 sA0 = __builtin_amdgcn_mfma_f32_16x16x32_bf16(kf0, qfA, zf, 0, 0, 0);
            floatx4 sA1 = __builtin_amdgcn_mfma_f32_16x16x32_bf16(kf1, qfA, zf, 0, 0, 0);
            floatx4 sB0 = __builtin_amdgcn_mfma_f32_16x16x32_bf16(kf0, qfB, zf, 0, 0, 0);
            floatx4 sB1 = __builtin_amdgcn_mfma_f32_16x16x32_bf16(kf1, qfB, zf, 0, 0, 0);

            floatx4 pA0, pA1, pB0, pB1;
            #pragma unroll
            for (int r = 0; r < 4; r++) {
                pA0[r] = __builtin_amdgcn_exp2f(sA0[r]);
                pA1[r] = __builtin_amdgcn_exp2f(sA1[r]);
                pB0[r] = __builtin_amdgcn_exp2f(sB0[r]);
                pB1[r] = __builtin_amdgcn_exp2f(sB1[r]);
            }

            // pack key pairs and transpose quads in-register
            short8 pfA = quad_xpose(pack2(pA0[0], pA0[1]), pack2(pA0[2], pA0[3]),
                                    pack2(pA1[0], pA1[1]), pack2(pA1[2], pA1[3]), lane);
            short8 pfB = quad_xpose(pack2(pB0[0], pB0[1]), pack2(pB0[2], pB0[3]),
                                    pack2(pB1[0], pB1[1]), pack2(pB1[2], pB1[3]), lane);

            short8 vf0 = *(short8*)&V_lds[cur][l15 * VS + jb + quad * 8];
            short8 vf1 = *(short8*)&V_lds[cur][(16 + l15) * VS + jb + quad * 8];
            accA0 = __builtin_amdgcn_mfma_f32_16x16x32_bf16(pfA, vf0, accA0, 0, 0, 0);
            accA1 = __builtin_amdgcn_mfma_f32_16x16x32_bf16(pfA, vf1, accA1, 0, 0, 0);
            accB0 = __builtin_amdgcn_mfma_f32_16x16x32_bf16(pfB, vf0, accB0, 0, 0, 0);
            accB1 = __builtin_amdgcn_mfma_f32_16x16x32_bf16(pfB, vf1, accB1, 0, 0, 0);
            // denominator on the MFMA pipe: every output col = row-sum of P
            denA  = __builtin_amdgcn_mfma_f32_16x16x32_bf16(pfA, onesf, denA, 0, 0, 0);
            denB  = __builtin_amdgcn_mfma_f32_16x16x32_bf16(pfB, onesf, denB, 0, 0, 0);
        }

        if (t + 1 < nt) {
            // stage tile t+1 (regs loaded 1 tile ago -> vmcnt satisfied long ago)
            *(short8*)&K_lds[cur ^ 1][kst]           = kregA;
            *(short8*)&K_lds[cur ^ 1][kst + 64 * KS] = kregB;
            *(short8*)&V_lds[cur ^ 1][vst]           = vregA;
            *(short8*)&V_lds[cur ^ 1][vst + 64]      = vregB;
            if (t + 2 < nt) {   // depth-2 prefetch
                const long jn = j_lo + (long)(t + 2) * 128;
                kregA = *(const short8*)(Kh + jn * HD + tid * 8);
                kregB = *(const short8*)(Kh + (jn + 64) * HD + tid * 8);
                vregA = *(const short8*)(Vh + vgl + jn);
                vregB = *(const short8*)(Vh + vgl + jn + 64);
            }
            __syncthreads();   // one barrier per tile: orders write(buf^1) vs read
        }
    }

    // denA[r] holds denom(query i0+quad*4+r), replicated across the 16 l15
    // lanes of the quad — exactly the C-frag row layout the epilogue needs.
    const int b = bh >> 2, h = bh & 3;
    unsigned short* AOz = AO + (long)z * (NBAT * N_TOK * A_DIM);
    float* Lz = Lbuf + (long)z * (BH * N_TOK);
    if (l15 == 0) {   // one lane per quad writes 4+4 denominators
        #pragma unroll
        for (int r = 0; r < 4; r++) {
            Lz[(long)bh * N_TOK + i0 + quad * 4 + r]      = denA[r];
            Lz[(long)bh * N_TOK + i0 + 16 + quad * 4 + r] = denB[r];
        }
    }
    #pragma unroll
    for (int r = 0; r < 4; r++) {
        const float invA = 1.0f / denA[r];
        const float invB = 1.0f / denB[r];
        const long rowA = (long)b * N_TOK + i0 + quad * 4 + r;
        const long rowB = rowA + 16;
        AOz[rowA * A_DIM + h * HD + l15]      = f2bf(accA0[r] * invA);
        AOz[rowA * A_DIM + h * HD + 16 + l15] = f2bf(accA1[r] * invA);
        AOz[rowB * A_DIM + h * HD + l15]      = f2bf(accB0[r] * invB);
        AOz[rowB * A_DIM + h * HD + 16 + l15] = f2bf(accB1[r] * invB);
    }
}

// ---------------------------------------------------------------------------
// K3: split-K combine + out-projection via MFMA. 512 blocks x 4 waves
// (unchanged from R9).
// ---------------------------------------------------------------------------
__global__ __launch_bounds__(256) void outproj_kernel(
    const unsigned short* __restrict__ AO, const float* __restrict__ Lbuf,
    const unsigned short* __restrict__ Wp, float* __restrict__ out)
{
    const int tid = threadIdx.x;
    const int w = tid >> 6, lane = tid & 63;
    const int quad = lane >> 4, l15 = lane & 15;
    const int ch = w;                       // col quarter (64 cols)
    const long i0 = (long)blockIdx.x * 16;
    const long row = i0 + l15;
    const int b = (int)(row >> 12);
    const int n = (int)(row & (N_TOK - 1));
    const unsigned short* Wop = Wp + 98304;

    floatx4 acc[4] = {};

    #pragma unroll
    for (int s = 0; s < 4; s++) {   // k-step == head s (32-aligned)
        float lz[SPLITS], lsum = 0.f;
        #pragma unroll
        for (int z = 0; z < SPLITS; z++) {
            lz[z] = Lbuf[(long)z * (BH * N_TOK) + (long)(b * HEADS + s) * N_TOK + n];
            lsum += lz[z];
        }
        const float inv = 1.0f / lsum;
        float vals[8] = {};
        #pragma unroll
        for (int z = 0; z < SPLITS; z++) {
            short8 az = *(const short8*)(AO + (long)z * (NBAT * N_TOK * A_DIM) +
                                         row * A_DIM + s * 32 + quad * 8);
            const float wz = lz[z] * inv;
            #pragma unroll
            for (int j = 0; j < 8; j++) vals[j] += wz * bf2f((unsigned short)az[j]);
        }
        union { unsigned int u[4]; short8 s8; } af;
        af.u[0] = pack2(vals[0], vals[1]); af.u[1] = pack2(vals[2], vals[3]);
        af.u[2] = pack2(vals[4], vals[5]); af.u[3] = pack2(vals[6], vals[7]);
        #pragma unroll
        for (int tp = 0; tp < 4; tp++) {
            const int t = ch * 4 + tp;
            short8 bo = *(const short8*)(Wop + ((long)(s * 16 + t) * 64 + lane) * 8);
            acc[tp] = __builtin_amdgcn_mfma_f32_16x16x32_bf16(af.s8, bo, acc[tp], 0, 0, 0);
        }
    }

    #pragma unroll
    for (int tp = 0; tp < 4; tp++) {
        #pragma unroll
        for (int r = 0; r < 4; r++)
            out[(i0 + quad * 4 + r) * C_DIM + (ch * 4 + tp) * 16 + l15] = acc[tp][r];
    }
}

// ---------------------------------------------------------------------------
extern "C" void kernel_launch(void* const* d_in, const int* in_sizes, int n_in,
                              void* d_out, int out_size, void* d_ws, size_t ws_size,
                              hipStream_t stream)
{
    const float* query   = (const float*)d_in[0];
    const float* context = (const float*)d_in[1];
    const float* Wq      = (const float*)d_in[2];
    const float* Wk      = (const float*)d_in[3];
    const float* Wv      = (const float*)d_in[4];
    const float* Wo      = (const float*)d_in[5];
    float* out = (float*)d_out;

    char* ws = (char*)d_ws;
    unsigned short* Qb = (unsigned short*)(ws);                    // 2 MB [bh][n][32]
    unsigned short* Kb = (unsigned short*)(ws + (2 << 20));        // 2 MB [bh][n][32]
    unsigned short* Vb = (unsigned short*)(ws + (4 << 20));        // 2 MB [bh][32][n]
    unsigned short* AO = (unsigned short*)(ws + (6 << 20));        // 8 MB [4][b*n][128] bf16
    float*          Lb = (float*)(ws + (22 << 20));                // 512 KB [4][bh][n]
    unsigned short* Wp = (unsigned short*)(ws + (23 << 20));       // 256 KB packed

    wpack_kernel<<<dim3(64), dim3(256), 0, stream>>>(Wq, Wk, Wv, Wo, Wp);
    qkv_kernel<<<dim3(512), dim3(256), 0, stream>>>(query, context, Wp, Qb, Kb, Vb);
    attn_kernel<<<dim3(32 * BH * SPLITS), dim3(256), 0, stream>>>(
        Qb, Kb, Vb, AO, Lb);
    outproj_kernel<<<dim3(512), dim3(256), 0, stream>>>(AO, Lb, Wp, out);
}